// Round 1
// baseline (3955.038 us; speedup 1.0000x reference)
//
#include <hip/hip_runtime.h>
#include <math.h>

// LPKT recurrent knowledge tracing.
// Decomposition: one workgroup per batch element (B=64 WGs), entire 99-step
// recurrence in-kernel with __syncthreads() phase barriers. h state (129x128
// fp32, padded to 136 rows) lives transposed in LDS: hT[feature d][n].
// Dominant per-step op: h_pre @ W4h -> 8n x 8d register-tiled fp32 dot,
// hT from LDS (float4), W4h streamed from global (L2-resident, shared by all WGs).

#define BB    64
#define SS    100
#define NQ1   129
#define NPAD  136
#define DK    128
#define NTHREADS 320
#define NGROUPS  17   // 17 groups of 8 rows = 136 (rows 129..135 are zero pads)

__device__ __forceinline__ float frcp(float x) { return __builtin_amdgcn_rcpf(x); }

__device__ __forceinline__ float fsig(float x) {
    float t = __expf(-x);            // x<<0 -> t=inf -> rcp(inf)=0, correct
    return frcp(1.0f + t);
}
__device__ __forceinline__ float ftanh(float x) {
    x = fminf(20.0f, fmaxf(-20.0f, x));
    float t = __expf(-2.0f * x);
    return (1.0f - t) * frcp(1.0f + t);
}
__device__ __forceinline__ float wave_reduce(float v) {
    #pragma unroll
    for (int off = 32; off > 0; off >>= 1) v += __shfl_down(v, off);
    return v;
}

template<bool HLDS>
__global__ __launch_bounds__(NTHREADS)
void lpkt_kernel(const int* __restrict__ e_data, const int* __restrict__ a_data,
                 const int* __restrict__ it_data, const int* __restrict__ at_data,
                 const float* __restrict__ qm,  const float* __restrict__ h0,
                 const float* __restrict__ Ee,  const float* __restrict__ Eat,
                 const float* __restrict__ Eit,
                 const float* __restrict__ W1, const float* __restrict__ b1,
                 const float* __restrict__ W2, const float* __restrict__ b2,
                 const float* __restrict__ W3, const float* __restrict__ b3,
                 const float* __restrict__ W4, const float* __restrict__ b4,
                 const float* __restrict__ W5, const float* __restrict__ b5,
                 float* __restrict__ out, float* __restrict__ hws)
{
    const int b   = blockIdx.x;
    const int tid = threadIdx.x;

    extern __shared__ __align__(16) float dynsm[];
    float* hT = HLDS ? dynsm : (hws + (size_t)b * (DK * NPAD)); // hT[d*NPAD + n] = h[n][d]

    __shared__ __align__(16) float s_erow[DK], s_atrow[DK], s_itrow[DK], s_enext[DK];
    __shared__ float s_qA[NPAD], s_qB[NPAD];
    __shared__ float s_lA[DK], s_lB[DK];
    __shared__ float s_htA[DK], s_htB[DK];
    __shared__ float s_LG[DK], s_c[DK], s_s1[DK];
    __shared__ float s_red[2 * DK];
    __shared__ float s_htred[NGROUPS * DK];
    __shared__ float s_scal[4];   // [0]=q_next sum, [1],[2]=y partials, [3]=q0 sum

    const int td = tid & 15,  tn = tid >> 4;   // 16 d-groups x 20 n-groups (17 used)
    const int d0 = td * 8,    n0 = tn * 8;

    // ---------------- prologue ----------------
    for (int idx = tid; idx < DK * NPAD; idx += NTHREADS) hT[idx] = 0.0f;
    if (tid < DK) {                    // s1[d] = sum_k W1[256+k][d]  (a_rep folded)
        float z0 = 0.f, z1 = 0.f;
        for (int k = 0; k < DK; k += 2) {
            z0 += W1[(256 + k)     * DK + tid];
            z1 += W1[(256 + k + 1) * DK + tid];
        }
        s_s1[tid] = z0 + z1;
        s_lA[tid] = 0.0f;              // learning_pre at t=0
    }
    if (tid >= 128 && tid < 128 + NPAD) {
        int j = tid - 128;
        int e0 = e_data[b * SS];
        s_qA[j] = (j < NQ1) ? qm[(size_t)e0 * NQ1 + j] : 0.0f;
    }
    if (tid == 0) out[b * SS] = 0.0f;  // pred[:,0] = 0
    __syncthreads();

    // fill h0 into transposed layout (after zeroing sync)
    for (int idx = tid; idx < NQ1 * DK; idx += NTHREADS) {
        int n = idx >> 7, d = idx & 127;
        hT[d * NPAD + n] = h0[idx];
    }
    if (tid >= 256) {                  // q0 sum (wave 4)
        int j = tid - 256;
        float v = s_qA[j] + s_qA[j + 64] + ((j < 8) ? s_qA[128 + j] : 0.0f);
        v = wave_reduce(v);
        if (j == 0) s_scal[3] = v;
    }
    __syncthreads();
    if (!HLDS) __threadfence();

    if (tid < DK) {                    // ht0[d] = sum_n q0[n]*h0[n][d] / sum(q0)
        float s = 0.0f;
        for (int n = 0; n < NQ1; n++) s += s_qA[n] * hT[tid * NPAD + n];
        s_htA[tid] = s * frcp(s_scal[3]);
    }
    __syncthreads();

    // ---------------- recurrence ----------------
    for (int t = 0; t < SS - 1; t++) {
        const bool odd = (t & 1);
        float* qc  = odd ? s_qB  : s_qA;   // q_all[:, t]
        float* qn  = odd ? s_qA  : s_qB;   // q_all[:, t+1]
        float* lp  = odd ? s_lB  : s_lA;   // learning_pre
        float* lc  = odd ? s_lA  : s_lB;   // learning (this step)
        float* htp = odd ? s_htB : s_htA;  // h_tilde_pre
        float* htn = odd ? s_htA : s_htB;  // h_tilde (this step)

        const int   base = b * SS + t;
        const int   e_t  = e_data[base];
        const int   at_t = at_data[base];
        const int   it_t = it_data[base];
        const float afl  = (float)a_data[base];
        const int   e_nx = e_data[base + 1];

        // --- stage embedding rows + q_next ---
        {
            int w = tid >> 5, j = tid & 31;
            if      (w == 0) ((float4*)s_erow )[j] = ((const float4*)(Ee  + (size_t)e_t  * DK))[j];
            else if (w == 1) ((float4*)s_atrow)[j] = ((const float4*)(Eat + (size_t)at_t * DK))[j];
            else if (w == 2) ((float4*)s_itrow)[j] = ((const float4*)(Eit + (size_t)it_t * DK))[j];
            else if (w == 3) ((float4*)s_enext)[j] = ((const float4*)(Ee  + (size_t)e_nx * DK))[j];
            else if (tid >= 128 && tid < 128 + NPAD) {
                int q = tid - 128;
                qn[q] = (q < NQ1) ? qm[(size_t)e_nx * NQ1 + q] : 0.0f;
            }
        }
        __syncthreads();   // (1)

        // --- phase A partials (all_learning) + q_next sum ---
        if (tid < 256) {
            const int mat = tid >> 7, d = tid & 127;
            const float* row = mat ? s_atrow : s_erow;
            const float* W   = W1 + mat * DK * DK;
            float z0 = 0.f, z1 = 0.f;
            for (int k = 0; k < DK; k += 2) {
                z0 += row[k]     * W[k * DK + d];
                z1 += row[k + 1] * W[(k + 1) * DK + d];
            }
            s_red[tid] = z0 + z1;
        } else {
            int j = tid - 256;
            float v = qn[j] + qn[j + 64] + ((j < 8) ? qn[128 + j] : 0.0f);
            v = wave_reduce(v);
            if (j == 0) s_scal[0] = v;
        }
        __syncthreads();   // (2)
        if (tid < DK) lc[tid] = b1[tid] + afl * s_s1[tid] + s_red[tid] + s_red[DK + tid];
        __syncthreads();   // (3)

        // --- phase B: lg / gamma_l logits (feat . W2, feat . W3), feat in 4 segments ---
        if (tid < 256) {
            const int mat = tid >> 7, d = tid & 127;
            const float* W = mat ? W3 : W2;
            float z0 = 0.f, z1 = 0.f, z2 = 0.f, z3 = 0.f;
            for (int k = 0; k < DK; k++) {
                z0 += lp[k]      * W[k * DK + d];
                z1 += s_itrow[k] * W[(DK     + k) * DK + d];
                z2 += lc[k]      * W[(2 * DK + k) * DK + d];
                z3 += htp[k]     * W[(3 * DK + k) * DK + d];
            }
            s_red[tid] = (z0 + z1) + (z2 + z3);
        }
        __syncthreads();   // (4)
        if (tid < DK)
            s_LG[tid] = fsig(s_red[DK + tid] + b3[tid]) *
                        (ftanh(s_red[tid] + b2[tid]) + 1.0f) * 0.5f;
        __syncthreads();   // (5)

        // --- phase C: c[d] = b4 + LG.W4l + it.W4i ---
        if (tid < 256) {
            const int mat = tid >> 7, d = tid & 127;
            const float* row = mat ? s_itrow : s_LG;
            const float* W   = W4 + (DK + mat * DK) * DK;
            float z0 = 0.f, z1 = 0.f;
            for (int k = 0; k < DK; k += 2) {
                z0 += row[k]     * W[k * DK + d];
                z1 += row[k + 1] * W[(k + 1) * DK + d];
            }
            s_red[tid] = z0 + z1;
        }
        __syncthreads();   // (6)
        if (tid < DK) s_c[tid] = b4[tid] + s_red[tid] + s_red[DK + tid];
        __syncthreads();   // (7)

        // --- phase D dot: logits[n][d] = sum_k h[n][k] * W4h[k][d] ---
        float acc[8][8];
        if (tid < 272) {
            #pragma unroll
            for (int i = 0; i < 8; i++)
                #pragma unroll
                for (int j = 0; j < 8; j++) acc[i][j] = 0.0f;
            const float* wrow = W4 + d0;        // W4h row k, cols d0..d0+7
            const float* hrow = hT + n0;        // hT[k][n0..n0+7] = h[n0..n0+7][k]
            #pragma unroll 2
            for (int k = 0; k < DK; k++) {
                float4 ha = *(const float4*)(hrow);
                float4 hb = *(const float4*)(hrow + 4);
                float4 wa = *(const float4*)(wrow);
                float4 wb = *(const float4*)(wrow + 4);
                hrow += NPAD; wrow += DK;
                float hv[8] = {ha.x, ha.y, ha.z, ha.w, hb.x, hb.y, hb.z, hb.w};
                float wv[8] = {wa.x, wa.y, wa.z, wa.w, wb.x, wb.y, wb.z, wb.w};
                #pragma unroll
                for (int i = 0; i < 8; i++)
                    #pragma unroll
                    for (int j = 0; j < 8; j++) acc[i][j] += hv[i] * wv[j];
            }
        }
        __syncthreads();   // (8) all dots read hT before anyone writes it

        // --- phase D update: h = q_e*LG + sigmoid(logit+c)*h_pre ; partial h_tilde ---
        if (tid < 272) {
            float qcv[8], qnv[8];
            #pragma unroll
            for (int i = 0; i < 8; i++) { qcv[i] = qc[n0 + i]; qnv[i] = qn[n0 + i]; }
            #pragma unroll
            for (int j = 0; j < 8; j++) {
                const int d = d0 + j;
                const float cj = s_c[d], lgj = s_LG[d];
                float* hp = hT + d * NPAD + n0;
                float4 oa = *(const float4*)(hp);
                float4 ob = *(const float4*)(hp + 4);
                float ho[8] = {oa.x, oa.y, oa.z, oa.w, ob.x, ob.y, ob.z, ob.w};
                float ph = 0.0f;
                #pragma unroll
                for (int i = 0; i < 8; i++) {
                    float g  = fsig(acc[i][j] + cj);
                    float hn = qcv[i] * lgj + g * ho[i];
                    ho[i] = hn;
                    ph   += qnv[i] * hn;
                }
                *(float4*)(hp)     = make_float4(ho[0], ho[1], ho[2], ho[3]);
                *(float4*)(hp + 4) = make_float4(ho[4], ho[5], ho[6], ho[7]);
                s_htred[tn * DK + d] = ph;
            }
        }
        __syncthreads();   // (9)
        if (!HLDS) __threadfence();

        if (tid < DK) {    // h_tilde
            float s = 0.0f;
            #pragma unroll
            for (int g = 0; g < NGROUPS; g++) s += s_htred[g * DK + tid];
            htn[tid] = s * frcp(s_scal[0]);
        }
        __syncthreads();   // (10)

        // --- phase E: y = mean_d sigmoid([e_next, h_tilde] . W5 + b5) ---
        if (tid < 256) {
            const int mat = tid >> 7, d = tid & 127;
            const float* row = mat ? htn : s_enext;
            const float* W   = W5 + mat * DK * DK;
            float z0 = 0.f, z1 = 0.f;
            for (int k = 0; k < DK; k += 2) {
                z0 += row[k]     * W[k * DK + d];
                z1 += row[k + 1] * W[(k + 1) * DK + d];
            }
            s_red[tid] = z0 + z1;
        }
        __syncthreads();   // (11)
        if (tid < DK) {
            float v = fsig(s_red[tid] + s_red[DK + tid] + b5[tid]);
            v = wave_reduce(v);
            if ((tid & 63) == 0) s_scal[1 + (tid >> 6)] = v;
        }
        __syncthreads();   // (12)
        if (tid == 0) out[base + 1] = (s_scal[1] + s_scal[2]) * (1.0f / 128.0f);
        __syncthreads();   // (13) protect buffers before next staging
    }
}

extern "C" void kernel_launch(void* const* d_in, const int* in_sizes, int n_in,
                              void* d_out, int out_size, void* d_ws, size_t ws_size,
                              hipStream_t stream) {
    const int*   e_data  = (const int*)d_in[0];
    const int*   a_data  = (const int*)d_in[1];
    const int*   it_data = (const int*)d_in[2];
    const int*   at_data = (const int*)d_in[3];
    const float* qm  = (const float*)d_in[4];
    const float* h0  = (const float*)d_in[5];
    const float* Ee  = (const float*)d_in[6];
    const float* Eat = (const float*)d_in[7];
    const float* Eit = (const float*)d_in[8];
    const float* W1  = (const float*)d_in[9];
    const float* b1  = (const float*)d_in[10];
    const float* W2  = (const float*)d_in[11];
    const float* b2  = (const float*)d_in[12];
    const float* W3  = (const float*)d_in[13];
    const float* b3  = (const float*)d_in[14];
    const float* W4  = (const float*)d_in[15];
    const float* b4  = (const float*)d_in[16];
    const float* W5  = (const float*)d_in[17];
    const float* b5  = (const float*)d_in[18];
    float* out = (float*)d_out;
    float* hws = (float*)d_ws;

    const size_t dynbytes = (size_t)DK * NPAD * sizeof(float);   // 69,632 B
    int dev = 0;
    (void)hipGetDevice(&dev);
    int maxShm = 0;
    (void)hipDeviceGetAttribute(&maxShm, hipDeviceAttributeMaxSharedMemoryPerBlock, dev);
    // static shared is ~16.5 KB; require headroom for dynamic + static
    bool useLds = ((size_t)maxShm >= dynbytes + 24000);
    if (!useLds && ws_size < (size_t)BB * DK * NPAD * sizeof(float)) useLds = true;

    if (useLds) {
        (void)hipFuncSetAttribute(reinterpret_cast<const void*>(&lpkt_kernel<true>),
                                  hipFuncAttributeMaxDynamicSharedMemorySize,
                                  (int)dynbytes);
        lpkt_kernel<true><<<dim3(BB), dim3(NTHREADS), dynbytes, stream>>>(
            e_data, a_data, it_data, at_data, qm, h0, Ee, Eat, Eit,
            W1, b1, W2, b2, W3, b3, W4, b4, W5, b5, out, hws);
    } else {
        lpkt_kernel<false><<<dim3(BB), dim3(NTHREADS), 0, stream>>>(
            e_data, a_data, it_data, at_data, qm, h0, Ee, Eat, Eit,
            W1, b1, W2, b2, W3, b3, W4, b4, W5, b5, out, hws);
    }
}

// Round 2
// 2920.105 us; speedup vs baseline: 1.3544x; 1.3544x over previous
//
#include <hip/hip_runtime.h>
#include <math.h>

// LPKT: one WG (256 thr, 4 waves) per batch element, 99-step recurrence in-kernel.
// h state (129x128 fp32) lives in REGISTERS in MFMA C-layout (5 cb x 16 regs/lane).
// Gate matmul h@W4h runs on matrix cores: A = W4h^T bf16 fragments preloaded once
// (32 VGPR/lane, constant all steps); B = h^T bf16 rewritten each step into a 40KB
// LDS buffer stored in exact B-fragment order. GEMV phases read weights as coalesced
// float4 from a k-quad-interleaved repack in d_ws (prep kernel) and broadcast
// features LDS->SGPR via v_readlane.

#define BB   64
#define SS   100
#define NQ1  129
#define DK   128
#define NTH  256
#define WS_PREP_FLOATS 229376

typedef __attribute__((ext_vector_type(16))) float floatx16;
typedef __attribute__((ext_vector_type(8)))  short short8v;

__device__ __forceinline__ float frcp(float x) { return __builtin_amdgcn_rcpf(x); }
__device__ __forceinline__ float fsig(float x) { float t = __expf(-x); return frcp(1.0f + t); }
__device__ __forceinline__ float ftanh(float x) {
    x = fminf(20.0f, fmaxf(-20.0f, x));
    float t = __expf(-2.0f * x);
    return (1.0f - t) * frcp(1.0f + t);
}
__device__ __forceinline__ float rlf(float v, int s) {
    return __int_as_float(__builtin_amdgcn_readlane(__float_as_int(v), s));
}
__device__ __forceinline__ unsigned bfbits(float x) {   // fp32 -> bf16 RNE
    unsigned u = __float_as_uint(x);
    return (u + 0x7fffu + ((u >> 16) & 1u)) >> 16;
}

// ---- prep: repack weights into k-quad-interleaved [d]-coalesced layout --------
// dst[base + ((k>>2)*128 + d)*4 + (k&3)] = src[(koff+k)*128 + d]
__global__ void prep_kernel(const float* __restrict__ W1, const float* __restrict__ W2,
                            const float* __restrict__ W3, const float* __restrict__ W4,
                            const float* __restrict__ W5, float* __restrict__ ws) {
    int g = blockIdx.x * blockDim.x + threadIdx.x;
    if (g >= WS_PREP_FLOATS) return;
    const float* src; int base, koff, idx;
    if      (g < 16384)  { src = W1; base = 0;      koff = 0;   idx = g; }
    else if (g < 32768)  { src = W1; base = 16384;  koff = 128; idx = g - 16384; }
    else if (g < 98304)  { src = W2; base = 32768;  koff = 0;   idx = g - 32768; }
    else if (g < 163840) { src = W3; base = 98304;  koff = 0;   idx = g - 98304; }
    else if (g < 180224) { src = W4; base = 163840; koff = 128; idx = g - 163840; }
    else if (g < 196608) { src = W4; base = 180224; koff = 256; idx = g - 180224; }
    else if (g < 212992) { src = W5; base = 196608; koff = 0;   idx = g - 196608; }
    else                 { src = W5; base = 212992; koff = 128; idx = g - 212992; }
    int k = idx >> 7, d = idx & 127;
    ws[base + (((k >> 2) * 128 + d) << 2) + (k & 3)] = src[(size_t)(koff + k) * 128 + d];
}

// ---- main kernel --------------------------------------------------------------
__global__ __launch_bounds__(NTH, 1)
void lpkt_kernel(const int* __restrict__ e_data, const int* __restrict__ a_data,
                 const int* __restrict__ it_data, const int* __restrict__ at_data,
                 const float* __restrict__ qm,  const float* __restrict__ h0,
                 const float* __restrict__ Ee,  const float* __restrict__ Eat,
                 const float* __restrict__ Eit,
                 const float* __restrict__ W1, const float* __restrict__ b1,
                 const float* __restrict__ W2, const float* __restrict__ b2,
                 const float* __restrict__ W3, const float* __restrict__ b3,
                 const float* __restrict__ W4, const float* __restrict__ b4,
                 const float* __restrict__ W5, const float* __restrict__ b5,
                 float* __restrict__ out, const float* __restrict__ ws)
{
    const int b    = blockIdx.x;
    const int tid  = threadIdx.x;
    const int lane = tid & 63;
    const int w    = tid >> 6;        // wave id = A row-block (d-rows 32w..32w+31)
    const int h5   = lane >> 5;
    const int l31  = lane & 31;

    // B-fragment buffer: frag f = kb*5+cb (kb 0..7, cb 0..4), 1KB each.
    // element B[k][n]: lane' = (n&31)+32*((k>>3)&1), byte = lane'*16 + (k&7)*2
    __shared__ __align__(16) unsigned s_frag[10240];          // 40 KB
    __shared__ __align__(16) float s_feat[512];  // [0:128)=lp [128:256)=it [256:384)=lc [384:512)=h_tilde
    __shared__ __align__(16) float s_eat[256];   // [0:128)=e_row [128:256)=at_row
    __shared__ __align__(16) float s_enext[128];
    __shared__ float s_LG[128], s_c[128], s_s1[128];
    __shared__ float s_red[256];
    __shared__ float s_q[2][160];
    __shared__ float s_scal[4];

    float hreg[5][16];     // h state, MFMA C-layout: n=32cb+l31, d=32w+(r&3)+8*(r>>2)+4*h5
    short8v afr[8];        // W4h^T A-fragments (constant)

    // ---------------- prologue ----------------
    // A-frags: lane holds A[d=32w+l31][k=16kb+8*h5+j] = W4h[k][d]
    #pragma unroll
    for (int kb = 0; kb < 8; kb++) {
        short8v a;
        #pragma unroll
        for (int j = 0; j < 8; j++) {
            int k = 16 * kb + 8 * h5 + j;
            float v = W4[(size_t)k * DK + 32 * w + l31];
            a[j] = (short)bfbits(v);
        }
        afr[kb] = a;
    }
    // h0 into registers + initial B-fragments
    #pragma unroll
    for (int cb = 0; cb < 5; cb++) {
        int n = 32 * cb + l31;
        #pragma unroll
        for (int r = 0; r < 16; r++) {
            int d = 32 * w + (r & 3) + 8 * (r >> 2) + 4 * h5;
            hreg[cb][r] = (n <= 128) ? h0[(size_t)n * DK + d] : 0.0f;
        }
        #pragma unroll
        for (int q = 0; q < 4; q++) {
            int kb = 2 * w + (q >> 1);
            int lanep = l31 + ((q & 1) << 5);
            int off = (((kb * 5 + cb) << 10) + lanep * 16 + (h5 << 3)) >> 2;
            unsigned lo = bfbits(hreg[cb][4 * q])     | (bfbits(hreg[cb][4 * q + 1]) << 16);
            unsigned hi = bfbits(hreg[cb][4 * q + 2]) | (bfbits(hreg[cb][4 * q + 3]) << 16);
            s_frag[off] = lo; s_frag[off + 1] = hi;
        }
    }
    if (tid < 128) {   // s1[d] = colsum of W1 a-part
        float z0 = 0.f, z1 = 0.f;
        for (int k = 0; k < 128; k += 2) {
            z0 += W1[(size_t)(256 + k) * DK + tid];
            z1 += W1[(size_t)(257 + k) * DK + tid];
        }
        s_s1[tid] = z0 + z1;
        s_feat[tid] = 0.0f;            // learning_pre = 0
    }
    {   int e0 = e_data[b * SS];
        if (tid < 160) s_q[0][tid] = (tid < NQ1) ? qm[(size_t)e0 * NQ1 + tid] : 0.0f; }
    if (tid == 0) out[b * SS] = 0.0f;
    __syncthreads();
    if (w == 3) {      // q0 sum
        float v = s_q[0][lane] + s_q[0][64 + lane] + ((lane < 32) ? s_q[0][128 + lane] : 0.0f);
        #pragma unroll
        for (int m = 32; m > 0; m >>= 1) v += __shfl_xor(v, m);
        if (lane == 0) s_scal[0] = v;
    }
    __syncthreads();
    {   // ht0 = q0-weighted mean of h0 rows
        float inv = frcp(s_scal[0]);
        float ph[16];
        #pragma unroll
        for (int r = 0; r < 16; r++) ph[r] = 0.0f;
        #pragma unroll
        for (int cb = 0; cb < 5; cb++) {
            float qv = s_q[0][32 * cb + l31];
            #pragma unroll
            for (int r = 0; r < 16; r++) ph[r] += qv * hreg[cb][r];
        }
        #pragma unroll
        for (int r = 0; r < 16; r++) {
            float v = ph[r];
            v += __shfl_xor(v, 1); v += __shfl_xor(v, 2); v += __shfl_xor(v, 4);
            v += __shfl_xor(v, 8); v += __shfl_xor(v, 16);
            if (l31 == 0) s_feat[384 + 32 * w + (r & 3) + 8 * (r >> 2) + 4 * h5] = v * inv;
        }
    }
    __syncthreads();

    // ---------------- recurrence ----------------
    for (int t = 0; t < SS - 1; t++) {
        const float* qcur = s_q[t & 1];
        float*       qnxt = s_q[(t + 1) & 1];
        const int base = b * SS + t;
        const int e_t  = e_data[base];
        const int at_t = at_data[base];
        const int it_t = it_data[base];
        const float afl = (float)a_data[base];
        const int e_nx = e_data[base + 1];

        // --- MFMA issue: logits[n][d] from previous step's fragments ---
        floatx16 acc[5];
        #pragma unroll
        for (int cb = 0; cb < 5; cb++) {
            floatx16 a = (floatx16)(0.0f);
            #pragma unroll
            for (int kb = 0; kb < 8; kb++) {
                short8v bf = *(const short8v*)((const char*)s_frag + (((kb * 5 + cb) << 10) + lane * 16));
                a = __builtin_amdgcn_mfma_f32_32x32x16_bf16(afr[kb], bf, a, 0, 0, 0);
            }
            acc[cb] = a;
        }

        // --- stage: embedding rows + q_next ---
        {
            const float* src; float* dst;
            if      (w == 0) { src = Ee  + (size_t)e_t  * DK; dst = s_eat; }
            else if (w == 1) { src = Eat + (size_t)at_t * DK; dst = s_eat + 128; }
            else if (w == 2) { src = Eit + (size_t)it_t * DK; dst = s_feat + 128; }
            else             { src = Ee  + (size_t)e_nx * DK; dst = s_enext; }
            ((float2*)dst)[lane] = ((const float2*)src)[lane];
            if (tid < 160) qnxt[tid] = (tid < NQ1) ? qm[(size_t)e_nx * NQ1 + tid] : 0.0f;
        }
        __syncthreads();   // B1

        // --- phase A: all_learning partials (+ wave3: q_next sum) ---
        if (w == 3) {
            float v = qnxt[lane] + qnxt[64 + lane] + ((lane < 32) ? qnxt[128 + lane] : 0.0f);
            #pragma unroll
            for (int m = 32; m > 0; m >>= 1) v += __shfl_xor(v, m);
            if (lane == 0) s_scal[0] = v;
        }
        {
            const int mat = tid >> 7, d = tid & 127;
            float4 fv = ((const float4*)s_eat)[lane];
            const float4* Wr = (const float4*)(ws + mat * 16384);
            float z0 = 0.f, z1 = 0.f, z2 = 0.f, z3 = 0.f;
            for (int s = 0; s < 32; s++) {
                float4 wv = Wr[s * 128 + d];
                int src = mat * 32 + s;
                z0 += rlf(fv.x, src) * wv.x;  z1 += rlf(fv.y, src) * wv.y;
                z2 += rlf(fv.z, src) * wv.z;  z3 += rlf(fv.w, src) * wv.w;
            }
            s_red[tid] = (z0 + z1) + (z2 + z3);
        }
        __syncthreads();   // B2
        if (tid < 128) s_feat[256 + tid] = b1[tid] + afl * s_s1[tid] + s_red[tid] + s_red[128 + tid];
        __syncthreads();   // B3

        // --- phase B: feat(512) . W2 / W3 ---
        {
            const int mat = tid >> 7, d = tid & 127;
            float4 fa = ((const float4*)s_feat)[2 * lane];
            float4 fb = ((const float4*)s_feat)[2 * lane + 1];
            const float4* Wr = (const float4*)(ws + 32768 + mat * 65536);
            float z0 = 0.f, z1 = 0.f, z2 = 0.f, z3 = 0.f;
            for (int s = 0; s < 64; s++) {
                float4 w0 = Wr[(2 * s) * 128 + d];
                float4 w1 = Wr[(2 * s + 1) * 128 + d];
                z0 += rlf(fa.x, s) * w0.x;  z1 += rlf(fa.y, s) * w0.y;
                z2 += rlf(fa.z, s) * w0.z;  z3 += rlf(fa.w, s) * w0.w;
                z0 += rlf(fb.x, s) * w1.x;  z1 += rlf(fb.y, s) * w1.y;
                z2 += rlf(fb.z, s) * w1.z;  z3 += rlf(fb.w, s) * w1.w;
            }
            s_red[tid] = (z0 + z1) + (z2 + z3);
        }
        __syncthreads();   // B4
        if (tid < 128) {
            s_LG[tid] = fsig(s_red[128 + tid] + b3[tid]) * (ftanh(s_red[tid] + b2[tid]) + 1.0f) * 0.5f;
            s_feat[tid] = s_feat[256 + tid];        // lp <- lc for next step
        }
        __syncthreads();   // B5

        // --- phase C: LG.W4l + it.W4i ---
        {
            const int mat = tid >> 7, d = tid & 127;
            const float* cp = (lane < 32) ? (s_LG + 4 * lane) : (s_feat + 4 * lane);
            float4 fv = *(const float4*)cp;
            const float4* Wr = (const float4*)(ws + 163840 + mat * 16384);
            float z0 = 0.f, z1 = 0.f, z2 = 0.f, z3 = 0.f;
            for (int s = 0; s < 32; s++) {
                float4 wv = Wr[s * 128 + d];
                int src = mat * 32 + s;
                z0 += rlf(fv.x, src) * wv.x;  z1 += rlf(fv.y, src) * wv.y;
                z2 += rlf(fv.z, src) * wv.z;  z3 += rlf(fv.w, src) * wv.w;
            }
            s_red[tid] = (z0 + z1) + (z2 + z3);
        }
        __syncthreads();   // B6
        if (tid < 128) s_c[tid] = b4[tid] + s_red[tid] + s_red[128 + tid];
        __syncthreads();   // B7

        // --- update: h = q*LG + sigmoid(logit+c)*h ; fragments + h_tilde ---
        {
            float inv = frcp(s_scal[0]);
            float lgv[16], cv[16];
            #pragma unroll
            for (int r = 0; r < 16; r++) {
                int d = 32 * w + (r & 3) + 8 * (r >> 2) + 4 * h5;
                lgv[r] = s_LG[d];  cv[r] = s_c[d];
            }
            float ph[16];
            #pragma unroll
            for (int r = 0; r < 16; r++) ph[r] = 0.0f;
            #pragma unroll
            for (int cb = 0; cb < 5; cb++) {
                int n = 32 * cb + l31;
                float qcv = qcur[n];
                float qnv = qnxt[n];
                bool valid = (cb < 4) || (l31 == 0);
                #pragma unroll
                for (int r = 0; r < 16; r++) {
                    float g  = fsig(acc[cb][r] + cv[r]);
                    float hn = qcv * lgv[r] + g * hreg[cb][r];
                    hn = valid ? hn : 0.0f;
                    hreg[cb][r] = hn;
                    ph[r] += qnv * hn;
                }
                #pragma unroll
                for (int q = 0; q < 4; q++) {
                    int kb = 2 * w + (q >> 1);
                    int lanep = l31 + ((q & 1) << 5);
                    int off = (((kb * 5 + cb) << 10) + lanep * 16 + (h5 << 3)) >> 2;
                    unsigned lo = bfbits(hreg[cb][4 * q])     | (bfbits(hreg[cb][4 * q + 1]) << 16);
                    unsigned hi = bfbits(hreg[cb][4 * q + 2]) | (bfbits(hreg[cb][4 * q + 3]) << 16);
                    s_frag[off] = lo; s_frag[off + 1] = hi;
                }
            }
            #pragma unroll
            for (int r = 0; r < 16; r++) {
                float v = ph[r];
                v += __shfl_xor(v, 1); v += __shfl_xor(v, 2); v += __shfl_xor(v, 4);
                v += __shfl_xor(v, 8); v += __shfl_xor(v, 16);
                if (l31 == 0) s_feat[384 + 32 * w + (r & 3) + 8 * (r >> 2) + 4 * h5] = v * inv;
            }
        }
        __syncthreads();   // B8

        // --- phase E: [e_next, h_tilde] . W5 ---
        {
            const int mat = tid >> 7, d = tid & 127;
            const float* cp = (lane < 32) ? (s_enext + 4 * lane) : (s_feat + 256 + 4 * lane);
            float4 fv = *(const float4*)cp;
            const float4* Wr = (const float4*)(ws + 196608 + mat * 16384);
            float z0 = 0.f, z1 = 0.f, z2 = 0.f, z3 = 0.f;
            for (int s = 0; s < 32; s++) {
                float4 wv = Wr[s * 128 + d];
                int src = mat * 32 + s;
                z0 += rlf(fv.x, src) * wv.x;  z1 += rlf(fv.y, src) * wv.y;
                z2 += rlf(fv.z, src) * wv.z;  z3 += rlf(fv.w, src) * wv.w;
            }
            s_red[tid] = (z0 + z1) + (z2 + z3);
        }
        __syncthreads();   // B9
        if (tid < 64) {    // y = mean_d sigmoid(logit)
            float v = fsig(s_red[lane]      + s_red[128 + lane] + b5[lane]) +
                      fsig(s_red[64 + lane] + s_red[192 + lane] + b5[64 + lane]);
            #pragma unroll
            for (int m = 32; m > 0; m >>= 1) v += __shfl_xor(v, m);
            if (lane == 0) out[base + 1] = v * (1.0f / 128.0f);
        }
        // no barrier: next stage writes don't conflict with y-wave reads (s_red only)
    }
}

extern "C" void kernel_launch(void* const* d_in, const int* in_sizes, int n_in,
                              void* d_out, int out_size, void* d_ws, size_t ws_size,
                              hipStream_t stream) {
    const int*   e_data  = (const int*)d_in[0];
    const int*   a_data  = (const int*)d_in[1];
    const int*   it_data = (const int*)d_in[2];
    const int*   at_data = (const int*)d_in[3];
    const float* qm  = (const float*)d_in[4];
    const float* h0  = (const float*)d_in[5];
    const float* Ee  = (const float*)d_in[6];
    const float* Eat = (const float*)d_in[7];
    const float* Eit = (const float*)d_in[8];
    const float* W1  = (const float*)d_in[9];
    const float* b1  = (const float*)d_in[10];
    const float* W2  = (const float*)d_in[11];
    const float* b2  = (const float*)d_in[12];
    const float* W3  = (const float*)d_in[13];
    const float* b3  = (const float*)d_in[14];
    const float* W4  = (const float*)d_in[15];
    const float* b4  = (const float*)d_in[16];
    const float* W5  = (const float*)d_in[17];
    const float* b5  = (const float*)d_in[18];
    float* out = (float*)d_out;
    float* ws  = (float*)d_ws;

    prep_kernel<<<dim3((WS_PREP_FLOATS + 255) / 256), dim3(256), 0, stream>>>(W1, W2, W3, W4, W5, ws);
    lpkt_kernel<<<dim3(BB), dim3(NTH), 0, stream>>>(
        e_data, a_data, it_data, at_data, qm, h0, Ee, Eat, Eit,
        W1, b1, W2, b2, W3, b3, W4, b4, W5, b5, out, ws);
}

// Round 3
// 2530.293 us; speedup vs baseline: 1.5631x; 1.1541x over previous
//
#include <hip/hip_runtime.h>
#include <math.h>

// LPKT: one WG (512 thr, 8 waves) per batch element, 99-step recurrence in-kernel.
// h state (129x128 fp32) in registers, MFMA C-layout, split across half-workgroups:
// half 0 (waves 0-3) holds cb{0,1,2}, half 1 (waves 4-7) cb{3,4}; wave's d-block = 32*(w&3).
// Gate matmul h@W4h on matrix cores, issued AFTER phase C with short acc live range
// (R2's step-top issue caused VGPR=256 + 24MB of spill traffic). GEMV phases split
// the k-range across halves (LDS combine) and read weights as coalesced float4 from
// a k-quad-interleaved repack in d_ws; features broadcast LDS->SGPR via v_readlane.

#define BB   64
#define SS   100
#define NQ1  129
#define DK   128
#define NTH  512
#define WS_W_FLOATS 229376
#define WS_TOTAL    237568   // + 8192 dwords of packed A-fragments

typedef __attribute__((ext_vector_type(16))) float floatx16;
typedef __attribute__((ext_vector_type(8)))  short short8v;

__device__ __forceinline__ float frcp(float x) { return __builtin_amdgcn_rcpf(x); }
__device__ __forceinline__ float fsig(float x) { float t = __expf(-x); return frcp(1.0f + t); }
__device__ __forceinline__ float ftanh(float x) {
    x = fminf(20.0f, fmaxf(-20.0f, x));
    float t = __expf(-2.0f * x);
    return (1.0f - t) * frcp(1.0f + t);
}
__device__ __forceinline__ float rlf(float v, int s) {
    return __int_as_float(__builtin_amdgcn_readlane(__float_as_int(v), s));
}
__device__ __forceinline__ unsigned bfbits(float x) {   // fp32 -> bf16 RNE
    unsigned u = __float_as_uint(x);
    return (u + 0x7fffu + ((u >> 16) & 1u)) >> 16;
}

// ---- prep: repack weights + pack W4h A-fragments -----------------------------
__global__ void prep_kernel(const float* __restrict__ W1, const float* __restrict__ W2,
                            const float* __restrict__ W3, const float* __restrict__ W4,
                            const float* __restrict__ W5, float* __restrict__ ws) {
    int gidx = blockIdx.x * blockDim.x + threadIdx.x;
    if (gidx < WS_W_FLOATS) {
        const float* src; int base, koff, idx;
        if      (gidx < 16384)  { src = W1; base = 0;      koff = 0;   idx = gidx; }
        else if (gidx < 32768)  { src = W1; base = 16384;  koff = 128; idx = gidx - 16384; }
        else if (gidx < 98304)  { src = W2; base = 32768;  koff = 0;   idx = gidx - 32768; }
        else if (gidx < 163840) { src = W3; base = 98304;  koff = 0;   idx = gidx - 98304; }
        else if (gidx < 180224) { src = W4; base = 163840; koff = 128; idx = gidx - 163840; }
        else if (gidx < 196608) { src = W4; base = 180224; koff = 256; idx = gidx - 180224; }
        else if (gidx < 212992) { src = W5; base = 196608; koff = 0;   idx = gidx - 212992 + 16384; }
        else                    { src = W5; base = 212992; koff = 128; idx = gidx - 212992; }
        if (gidx >= 196608 && gidx < 212992) idx = gidx - 196608;   // fix W5a idx
        int k = idx >> 7, d = idx & 127;
        ws[base + (((k >> 2) * 128 + d) << 2) + (k & 3)] = src[(size_t)(koff + k) * 128 + d];
    } else if (gidx < WS_TOTAL) {
        // A-fragment pack: dword i -> (g, kb, lane, c); elems j=2c,2c+1: k=16kb+8*(lane>>5)+j
        int i = gidx - WS_W_FLOATS;
        int gg = i >> 11, kb = (i >> 8) & 7, lane = (i >> 2) & 63, c = i & 3;
        int m = lane & 31, hp = lane >> 5;
        int k0 = 16 * kb + 8 * hp + 2 * c;
        unsigned lo = bfbits(W4[(size_t)k0 * 128 + 32 * gg + m]);
        unsigned hi = bfbits(W4[(size_t)(k0 + 1) * 128 + 32 * gg + m]);
        ((unsigned*)ws)[gidx] = lo | (hi << 16);
    }
}

// ---- main kernel --------------------------------------------------------------
__global__ __launch_bounds__(NTH, 2)
void lpkt_kernel(const int* __restrict__ e_data, const int* __restrict__ a_data,
                 const int* __restrict__ it_data, const int* __restrict__ at_data,
                 const float* __restrict__ qm,  const float* __restrict__ h0,
                 const float* __restrict__ Ee,  const float* __restrict__ Eat,
                 const float* __restrict__ Eit,
                 const float* __restrict__ W1, const float* __restrict__ b1,
                 const float* __restrict__ W2, const float* __restrict__ b2,
                 const float* __restrict__ W3, const float* __restrict__ b3,
                 const float* __restrict__ W4, const float* __restrict__ b4,
                 const float* __restrict__ W5, const float* __restrict__ b5,
                 float* __restrict__ out, const float* __restrict__ ws)
{
    const int b    = blockIdx.x;
    const int tid  = threadIdx.x;
    const int lane = tid & 63;
    const int w    = tid >> 6;
    const int g    = w & 3;          // MFMA d-block: rows 32g..32g+31
    const int hh   = w >> 2;         // half: cb set + GEMV k-half
    const int h5   = lane >> 5;
    const int l31  = lane & 31;
    const int ncb  = hh ? 2 : 3;
    const int cb0  = hh ? 3 : 0;
    const int gd   = ((w & 1) << 6) | lane;   // GEMV output d
    const int gmat = (w >> 1) & 1;            // GEMV matrix select

    __shared__ __align__(16) unsigned s_frag[10240];  // 40 KB B-fragments (kb*5+cb)
    __shared__ __align__(16) float s_feat[512];   // [lp | it | lc | h_tilde]
    __shared__ __align__(16) float s_eat[256];    // [e_row | at_row]
    __shared__ __align__(16) float s_enext[128];
    __shared__ float s_LG[128], s_c[128], s_s1[128];
    __shared__ __align__(16) float s_red[512];    // (hh*2+mat)*128 + d
    __shared__ float s_ht2[2][128];
    __shared__ float s_q[2][160];
    __shared__ float s_scal[2];

    float hreg[3][16];    // n = 32*(cb0+i)+l31, d = 32g+(r&3)+8*(r>>2)+4*h5
    short8v afr[8];       // A-fragments for d-block g (constant all steps)

    // ---------------- prologue ----------------
    #pragma unroll
    for (int kb = 0; kb < 8; kb++)
        afr[kb] = *(const short8v*)(((const uint4*)ws) + 57344 + g * 512 + kb * 64 + lane);

    #pragma unroll
    for (int i = 0; i < 3; i++) {
        if (i < ncb) {
            int cb = cb0 + i;
            int n = 32 * cb + l31;
            #pragma unroll
            for (int r = 0; r < 16; r++) {
                int d = 32 * g + (r & 3) + 8 * (r >> 2) + 4 * h5;
                hreg[i][r] = (n <= 128) ? h0[(size_t)n * DK + d] : 0.0f;
            }
            #pragma unroll
            for (int q = 0; q < 4; q++) {
                int kb = 2 * g + (q >> 1);
                int lanep = l31 + ((q & 1) << 5);
                int off = (((kb * 5 + cb) << 10) + lanep * 16 + (h5 << 3)) >> 2;
                unsigned lo = bfbits(hreg[i][4 * q])     | (bfbits(hreg[i][4 * q + 1]) << 16);
                unsigned hi = bfbits(hreg[i][4 * q + 2]) | (bfbits(hreg[i][4 * q + 3]) << 16);
                s_frag[off] = lo; s_frag[off + 1] = hi;
            }
        } else {
            #pragma unroll
            for (int r = 0; r < 16; r++) hreg[i][r] = 0.0f;
        }
    }
    {   // s1 partials: quarter = tid>>7
        int qt = tid >> 7, d = tid & 127;
        float z = 0.0f;
        for (int k = 32 * qt; k < 32 * qt + 32; k++) z += W1[(size_t)(256 + k) * DK + d];
        s_red[tid] = z;
    }
    if (tid < 160) {
        int e0 = e_data[b * SS];
        s_q[0][tid] = (tid < NQ1) ? qm[(size_t)e0 * NQ1 + tid] : 0.0f;
    }
    if (tid == 0) out[b * SS] = 0.0f;
    __syncthreads();
    if (tid < 128) {
        s_s1[tid] = s_red[tid] + s_red[128 + tid] + s_red[256 + tid] + s_red[384 + tid];
        s_feat[tid] = 0.0f;            // learning_pre = 0
    }
    if (w == 7) {
        float v = s_q[0][lane] + s_q[0][64 + lane] + ((lane < 32) ? s_q[0][128 + lane] : 0.0f);
        #pragma unroll
        for (int m = 32; m > 0; m >>= 1) v += __shfl_xor(v, m);
        if (lane == 0) s_scal[0] = v;
    }
    __syncthreads();
    {   // ht0 partials
        float ph[16];
        #pragma unroll
        for (int r = 0; r < 16; r++) ph[r] = 0.0f;
        for (int i = 0; i < ncb; i++) {
            float qv = s_q[0][32 * (cb0 + i) + l31];
            #pragma unroll
            for (int r = 0; r < 16; r++) ph[r] += qv * hreg[i][r];
        }
        #pragma unroll
        for (int r = 0; r < 16; r++) {
            float v = ph[r];
            v += __shfl_xor(v, 1); v += __shfl_xor(v, 2); v += __shfl_xor(v, 4);
            v += __shfl_xor(v, 8); v += __shfl_xor(v, 16);
            if (l31 == 0) s_ht2[hh][32 * g + (r & 3) + 8 * (r >> 2) + 4 * h5] = v;
        }
    }
    __syncthreads();
    if (tid < 128) s_feat[384 + tid] = (s_ht2[0][tid] + s_ht2[1][tid]) * frcp(s_scal[0]);
    __syncthreads();

    // ---------------- recurrence ----------------
    for (int t = 0; t < SS - 1; t++) {
        const float* qcur = s_q[t & 1];
        float*       qnxt = s_q[(t + 1) & 1];
        const int base = b * SS + t;
        const int e_t  = e_data[base];
        const int at_t = at_data[base];
        const int it_t = it_data[base];
        const float afl = (float)a_data[base];
        const int e_nx = e_data[base + 1];

        // --- staging ---
        if (w < 4) {
            const float* src; float* dst;
            if      (w == 0) { src = Ee  + (size_t)e_t  * DK; dst = s_eat; }
            else if (w == 1) { src = Eat + (size_t)at_t * DK; dst = s_eat + 128; }
            else if (w == 2) { src = Eit + (size_t)it_t * DK; dst = s_feat + 128; }
            else             { src = Ee  + (size_t)e_nx * DK; dst = s_enext; }
            ((float2*)dst)[lane] = ((const float2*)src)[lane];
        } else {
            int idx = tid - 256;
            if (idx < 160) qnxt[idx] = (idx < NQ1) ? qm[(size_t)e_nx * NQ1 + idx] : 0.0f;
        }
        __syncthreads();   // B1

        // --- phase A: all_learning partials (+ wave7 q_next sum) ---
        if (w == 7) {
            float v = qnxt[lane] + qnxt[64 + lane] + ((lane < 32) ? qnxt[128 + lane] : 0.0f);
            #pragma unroll
            for (int m = 32; m > 0; m >>= 1) v += __shfl_xor(v, m);
            if (lane == 0) s_scal[0] = v;
        }
        {
            const float4* rowp = (const float4*)(gmat ? (s_eat + 128) : s_eat);
            float4 fv = rowp[16 * hh + (lane & 15)];
            const float4* Wr = (const float4*)(ws + gmat * 16384);
            float z0 = 0.f, z1 = 0.f, z2 = 0.f, z3 = 0.f;
            #pragma unroll 8
            for (int s = 0; s < 16; s++) {
                float4 wv = Wr[(16 * hh + s) * 128 + gd];
                z0 += rlf(fv.x, s) * wv.x;  z1 += rlf(fv.y, s) * wv.y;
                z2 += rlf(fv.z, s) * wv.z;  z3 += rlf(fv.w, s) * wv.w;
            }
            s_red[(hh * 2 + gmat) * 128 + gd] = (z0 + z1) + (z2 + z3);
        }
        __syncthreads();   // B2
        if (tid < 128)
            s_feat[256 + tid] = b1[tid] + afl * s_s1[tid]
                              + s_red[tid] + s_red[128 + tid] + s_red[256 + tid] + s_red[384 + tid];
        __syncthreads();   // B3

        // --- phase B: feat(512) . W2 / W3, k split across halves ---
        {
            float4 fv = ((const float4*)s_feat)[64 * hh + lane];
            const float4* Wr = (const float4*)(ws + 32768 + gmat * 65536);
            float z0 = 0.f, z1 = 0.f, z2 = 0.f, z3 = 0.f;
            #pragma unroll 8
            for (int s = 0; s < 64; s++) {
                float4 wv = Wr[(64 * hh + s) * 128 + gd];
                z0 += rlf(fv.x, s) * wv.x;  z1 += rlf(fv.y, s) * wv.y;
                z2 += rlf(fv.z, s) * wv.z;  z3 += rlf(fv.w, s) * wv.w;
            }
            s_red[(hh * 2 + gmat) * 128 + gd] = (z0 + z1) + (z2 + z3);
        }
        __syncthreads();   // B4
        if (tid < 128) {
            float w2s = s_red[tid]       + s_red[256 + tid];
            float w3s = s_red[128 + tid] + s_red[384 + tid];
            s_LG[tid] = fsig(w3s + b3[tid]) * (ftanh(w2s + b2[tid]) + 1.0f) * 0.5f;
            s_feat[tid] = s_feat[256 + tid];   // lp <- lc
        }
        __syncthreads();   // B5

        // --- phase C: LG.W4l + it.W4i ---
        {
            const float4* rowp = (const float4*)(gmat ? (s_feat + 128) : s_LG);
            float4 fv = rowp[16 * hh + (lane & 15)];
            const float4* Wr = (const float4*)(ws + 163840 + gmat * 16384);
            float z0 = 0.f, z1 = 0.f, z2 = 0.f, z3 = 0.f;
            #pragma unroll 8
            for (int s = 0; s < 16; s++) {
                float4 wv = Wr[(16 * hh + s) * 128 + gd];
                z0 += rlf(fv.x, s) * wv.x;  z1 += rlf(fv.y, s) * wv.y;
                z2 += rlf(fv.z, s) * wv.z;  z3 += rlf(fv.w, s) * wv.w;
            }
            s_red[(hh * 2 + gmat) * 128 + gd] = (z0 + z1) + (z2 + z3);
        }
        __syncthreads();   // B6
        if (tid < 128)
            s_c[tid] = b4[tid] + s_red[tid] + s_red[128 + tid] + s_red[256 + tid] + s_red[384 + tid];
        __syncthreads();   // B7

        // --- MFMA: logits for this wave's cb set (short acc live range) ---
        floatx16 acc[3];
        #pragma unroll
        for (int i = 0; i < 3; i++) {
            if (i < ncb) {
                int cb = cb0 + i;
                floatx16 a = (floatx16)(0.0f);
                #pragma unroll
                for (int kb = 0; kb < 8; kb++) {
                    short8v bf = *(const short8v*)((const char*)s_frag + (((kb * 5 + cb) << 10) + lane * 16));
                    a = __builtin_amdgcn_mfma_f32_32x32x16_bf16(afr[kb], bf, a, 0, 0, 0);
                }
                acc[i] = a;
            }
        }
        __syncthreads();   // B8: all fragment reads done before rewrite

        // --- update: h = q*LG + sigmoid(logit+c)*h ; new fragments + h_tilde ---
        {
            float lgv[16], cv[16];
            #pragma unroll
            for (int r = 0; r < 16; r++) {
                int d = 32 * g + (r & 3) + 8 * (r >> 2) + 4 * h5;
                lgv[r] = s_LG[d];  cv[r] = s_c[d];
            }
            float ph[16];
            #pragma unroll
            for (int r = 0; r < 16; r++) ph[r] = 0.0f;
            for (int i = 0; i < ncb; i++) {
                int cb = cb0 + i;
                int n = 32 * cb + l31;
                float qcv = qcur[n];
                float qnv = qnxt[n];
                bool valid = (cb < 4) || (l31 == 0);
                #pragma unroll
                for (int r = 0; r < 16; r++) {
                    float gg = fsig(acc[i][r] + cv[r]);
                    float hn = qcv * lgv[r] + gg * hreg[i][r];
                    hn = valid ? hn : 0.0f;
                    hreg[i][r] = hn;
                    ph[r] += qnv * hn;
                }
                #pragma unroll
                for (int q = 0; q < 4; q++) {
                    int kb = 2 * g + (q >> 1);
                    int lanep = l31 + ((q & 1) << 5);
                    int off = (((kb * 5 + cb) << 10) + lanep * 16 + (h5 << 3)) >> 2;
                    unsigned lo = bfbits(hreg[i][4 * q])     | (bfbits(hreg[i][4 * q + 1]) << 16);
                    unsigned hi = bfbits(hreg[i][4 * q + 2]) | (bfbits(hreg[i][4 * q + 3]) << 16);
                    s_frag[off] = lo; s_frag[off + 1] = hi;
                }
            }
            #pragma unroll
            for (int r = 0; r < 16; r++) {
                float v = ph[r];
                v += __shfl_xor(v, 1); v += __shfl_xor(v, 2); v += __shfl_xor(v, 4);
                v += __shfl_xor(v, 8); v += __shfl_xor(v, 16);
                if (l31 == 0) s_ht2[hh][32 * g + (r & 3) + 8 * (r >> 2) + 4 * h5] = v;
            }
        }
        __syncthreads();   // B9
        if (tid < 128)
            s_feat[384 + tid] = (s_ht2[0][tid] + s_ht2[1][tid]) * frcp(s_scal[0]);
        __syncthreads();   // B10

        // --- phase E: [e_next, h_tilde] . W5 ---
        {
            const float4* rowp = (const float4*)(gmat ? (s_feat + 384) : s_enext);
            float4 fv = rowp[16 * hh + (lane & 15)];
            const float4* Wr = (const float4*)(ws + 196608 + gmat * 16384);
            float z0 = 0.f, z1 = 0.f, z2 = 0.f, z3 = 0.f;
            #pragma unroll 8
            for (int s = 0; s < 16; s++) {
                float4 wv = Wr[(16 * hh + s) * 128 + gd];
                z0 += rlf(fv.x, s) * wv.x;  z1 += rlf(fv.y, s) * wv.y;
                z2 += rlf(fv.z, s) * wv.z;  z3 += rlf(fv.w, s) * wv.w;
            }
            s_red[(hh * 2 + gmat) * 128 + gd] = (z0 + z1) + (z2 + z3);
        }
        __syncthreads();   // B11
        if (tid < 64) {
            float v = fsig(s_red[lane]      + s_red[128 + lane] + s_red[256 + lane] + s_red[384 + lane] + b5[lane])
                    + fsig(s_red[64 + lane] + s_red[192 + lane] + s_red[320 + lane] + s_red[448 + lane] + b5[64 + lane]);
            #pragma unroll
            for (int m = 32; m > 0; m >>= 1) v += __shfl_xor(v, m);
            if (lane == 0) out[base + 1] = v * (1.0f / 128.0f);
        }
        // no barrier needed: B1 of next iteration orders staging writes vs. readers
    }
}

extern "C" void kernel_launch(void* const* d_in, const int* in_sizes, int n_in,
                              void* d_out, int out_size, void* d_ws, size_t ws_size,
                              hipStream_t stream) {
    const int*   e_data  = (const int*)d_in[0];
    const int*   a_data  = (const int*)d_in[1];
    const int*   it_data = (const int*)d_in[2];
    const int*   at_data = (const int*)d_in[3];
    const float* qm  = (const float*)d_in[4];
    const float* h0  = (const float*)d_in[5];
    const float* Ee  = (const float*)d_in[6];
    const float* Eat = (const float*)d_in[7];
    const float* Eit = (const float*)d_in[8];
    const float* W1  = (const float*)d_in[9];
    const float* b1  = (const float*)d_in[10];
    const float* W2  = (const float*)d_in[11];
    const float* b2  = (const float*)d_in[12];
    const float* W3  = (const float*)d_in[13];
    const float* b3  = (const float*)d_in[14];
    const float* W4  = (const float*)d_in[15];
    const float* b4  = (const float*)d_in[16];
    const float* W5  = (const float*)d_in[17];
    const float* b5  = (const float*)d_in[18];
    float* out = (float*)d_out;
    float* ws  = (float*)d_ws;

    prep_kernel<<<dim3((WS_TOTAL + 255) / 256), dim3(256), 0, stream>>>(W1, W2, W3, W4, W5, ws);
    lpkt_kernel<<<dim3(BB), dim3(NTH), 0, stream>>>(
        e_data, a_data, it_data, at_data, qm, h0, Ee, Eat, Eit,
        W1, b1, W2, b2, W3, b3, W4, b4, W5, b5, out, ws);
}

// Round 4
// 2106.799 us; speedup vs baseline: 1.8773x; 1.2010x over previous
//
#include <hip/hip_runtime.h>
#include <math.h>

// LPKT: one WG (512 thr, 8 waves) per batch element, 99-step recurrence in-kernel.
// h state (129x128 fp32) in REGISTERS, MFMA C-layout, split across half-workgroups:
// half 0 (waves 0-3) holds cb{0,1,2}, half 1 (waves 4-7) cb{3,4}; wave's d-block = 32*(w&3).
// R3 bug fixed: all cb loops are #pragma unroll with LITERAL bound 3 + wave-uniform
// predicate (runtime trip count had demoted hreg/acc to scratch -> 557 MB HBM writes).
// Gate matmul h@W4h on matrix cores, issued at step top (acc is 48 VGPR, fits now);
// fragments read from a 40KB LDS buffer in exact B-fragment order. GEMV phases split
// the k-range across halves (LDS combine) and read weights as coalesced float4 from
// a k-quad-interleaved repack in d_ws; features broadcast LDS->SGPR via v_readlane.

#define BB   64
#define SS   100
#define NQ1  129
#define DK   128
#define NTH  512
#define WS_W_FLOATS 229376
#define WS_TOTAL    237568   // + 8192 dwords of packed A-fragments

typedef __attribute__((ext_vector_type(16))) float floatx16;
typedef __attribute__((ext_vector_type(8)))  short short8v;

__device__ __forceinline__ float frcp(float x) { return __builtin_amdgcn_rcpf(x); }
__device__ __forceinline__ float fsig(float x) { float t = __expf(-x); return frcp(1.0f + t); }
__device__ __forceinline__ float ftanh(float x) {
    x = fminf(20.0f, fmaxf(-20.0f, x));
    float t = __expf(-2.0f * x);
    return (1.0f - t) * frcp(1.0f + t);
}
__device__ __forceinline__ float rlf(float v, int s) {
    return __int_as_float(__builtin_amdgcn_readlane(__float_as_int(v), s));
}
__device__ __forceinline__ unsigned bfbits(float x) {   // fp32 -> bf16 RNE
    unsigned u = __float_as_uint(x);
    return (u + 0x7fffu + ((u >> 16) & 1u)) >> 16;
}

// ---- prep: repack weights + pack W4h A-fragments -----------------------------
__global__ void prep_kernel(const float* __restrict__ W1, const float* __restrict__ W2,
                            const float* __restrict__ W3, const float* __restrict__ W4,
                            const float* __restrict__ W5, float* __restrict__ ws) {
    int gidx = blockIdx.x * blockDim.x + threadIdx.x;
    if (gidx < WS_W_FLOATS) {
        const float* src; int base, koff, idx;
        if      (gidx < 16384)  { src = W1; base = 0;      koff = 0;   idx = gidx; }
        else if (gidx < 32768)  { src = W1; base = 16384;  koff = 128; idx = gidx - 16384; }
        else if (gidx < 98304)  { src = W2; base = 32768;  koff = 0;   idx = gidx - 32768; }
        else if (gidx < 163840) { src = W3; base = 98304;  koff = 0;   idx = gidx - 98304; }
        else if (gidx < 180224) { src = W4; base = 163840; koff = 128; idx = gidx - 163840; }
        else if (gidx < 196608) { src = W4; base = 180224; koff = 256; idx = gidx - 180224; }
        else if (gidx < 212992) { src = W5; base = 196608; koff = 0;   idx = gidx - 196608; }
        else                    { src = W5; base = 212992; koff = 128; idx = gidx - 212992; }
        int k = idx >> 7, d = idx & 127;
        ws[base + (((k >> 2) * 128 + d) << 2) + (k & 3)] = src[(size_t)(koff + k) * 128 + d];
    } else if (gidx < WS_TOTAL) {
        // A-fragment pack: dword i -> (g, kb, lane, c); elems j=2c,2c+1: k=16kb+8*(lane>>5)+j
        int i = gidx - WS_W_FLOATS;
        int gg = i >> 11, kb = (i >> 8) & 7, lane = (i >> 2) & 63, c = i & 3;
        int m = lane & 31, hp = lane >> 5;
        int k0 = 16 * kb + 8 * hp + 2 * c;
        unsigned lo = bfbits(W4[(size_t)k0 * 128 + 32 * gg + m]);
        unsigned hi = bfbits(W4[(size_t)(k0 + 1) * 128 + 32 * gg + m]);
        ((unsigned*)ws)[gidx] = lo | (hi << 16);
    }
}

// ---- main kernel --------------------------------------------------------------
__global__ __launch_bounds__(NTH, 2)
void lpkt_kernel(const int* __restrict__ e_data, const int* __restrict__ a_data,
                 const int* __restrict__ it_data, const int* __restrict__ at_data,
                 const float* __restrict__ qm,  const float* __restrict__ h0,
                 const float* __restrict__ Ee,  const float* __restrict__ Eat,
                 const float* __restrict__ Eit,
                 const float* __restrict__ W1, const float* __restrict__ b1,
                 const float* __restrict__ W2, const float* __restrict__ b2,
                 const float* __restrict__ W3, const float* __restrict__ b3,
                 const float* __restrict__ W4, const float* __restrict__ b4,
                 const float* __restrict__ W5, const float* __restrict__ b5,
                 float* __restrict__ out, const float* __restrict__ ws)
{
    const int b    = blockIdx.x;
    const int tid  = threadIdx.x;
    const int lane = tid & 63;
    const int w    = tid >> 6;
    const int g    = w & 3;          // MFMA d-block: rows 32g..32g+31
    const int hh   = w >> 2;         // half: cb set + GEMV k-half
    const int h5   = lane >> 5;
    const int l31  = lane & 31;
    const int ncb  = hh ? 2 : 3;
    const int cb0  = hh ? 3 : 0;
    const int gd   = ((w & 1) << 6) | lane;   // GEMV output d
    const int gmat = (w >> 1) & 1;            // GEMV matrix select

    __shared__ __align__(16) unsigned s_frag[10240];  // 40 KB B-fragments (kb*5+cb)
    __shared__ __align__(16) float s_feat[512];   // [lp | it | lc | h_tilde]
    __shared__ __align__(16) float s_eat[256];    // [e_row | at_row]
    __shared__ __align__(16) float s_enext[128];
    __shared__ float s_LG[128], s_c[128], s_s1[128];
    __shared__ __align__(16) float s_red[512];    // (hh*2+mat)*128 + d
    __shared__ float s_ht2[2][128];
    __shared__ float s_q[2][160];
    __shared__ float s_scal[2];

    float hreg[3][16];    // n = 32*(cb0+i)+l31, d = 32g+(r&3)+8*(r>>2)+4*h5
    short8v afr[8];       // A-fragments for d-block g (constant all steps)

    // ---------------- prologue ----------------
    #pragma unroll
    for (int kb = 0; kb < 8; kb++)
        afr[kb] = *(const short8v*)(((const uint4*)ws) + 57344 + g * 512 + kb * 64 + lane);

    #pragma unroll
    for (int i = 0; i < 3; i++) {
        if (i < ncb) {
            int cb = cb0 + i;
            int n = 32 * cb + l31;
            #pragma unroll
            for (int r = 0; r < 16; r++) {
                int d = 32 * g + (r & 3) + 8 * (r >> 2) + 4 * h5;
                hreg[i][r] = (n <= 128) ? h0[(size_t)n * DK + d] : 0.0f;
            }
            #pragma unroll
            for (int q = 0; q < 4; q++) {
                int kb = 2 * g + (q >> 1);
                int lanep = l31 + ((q & 1) << 5);
                int off = (((kb * 5 + cb) << 10) + lanep * 16 + (h5 << 3)) >> 2;
                unsigned lo = bfbits(hreg[i][4 * q])     | (bfbits(hreg[i][4 * q + 1]) << 16);
                unsigned hi = bfbits(hreg[i][4 * q + 2]) | (bfbits(hreg[i][4 * q + 3]) << 16);
                s_frag[off] = lo; s_frag[off + 1] = hi;
            }
        } else {
            #pragma unroll
            for (int r = 0; r < 16; r++) hreg[i][r] = 0.0f;
        }
    }
    {   // s1 partials: quarter = tid>>7
        int qt = tid >> 7, d = tid & 127;
        float z = 0.0f;
        for (int k = 32 * qt; k < 32 * qt + 32; k++) z += W1[(size_t)(256 + k) * DK + d];
        s_red[tid] = z;
    }
    if (tid < 160) {
        int e0 = e_data[b * SS];
        s_q[0][tid] = (tid < NQ1) ? qm[(size_t)e0 * NQ1 + tid] : 0.0f;
    }
    if (tid == 0) out[b * SS] = 0.0f;
    __syncthreads();
    if (tid < 128) {
        s_s1[tid] = s_red[tid] + s_red[128 + tid] + s_red[256 + tid] + s_red[384 + tid];
        s_feat[tid] = 0.0f;            // learning_pre = 0
    }
    if (w == 7) {
        float v = s_q[0][lane] + s_q[0][64 + lane] + ((lane < 32) ? s_q[0][128 + lane] : 0.0f);
        #pragma unroll
        for (int m = 32; m > 0; m >>= 1) v += __shfl_xor(v, m);
        if (lane == 0) s_scal[0] = v;
    }
    __syncthreads();
    {   // ht0 partials (fully unrolled, predicated)
        float ph[16];
        #pragma unroll
        for (int r = 0; r < 16; r++) ph[r] = 0.0f;
        #pragma unroll
        for (int i = 0; i < 3; i++) {
            const bool act = (i < ncb);
            const int cb = act ? (cb0 + i) : 0;
            float qv = act ? s_q[0][32 * cb + l31] : 0.0f;
            #pragma unroll
            for (int r = 0; r < 16; r++) ph[r] += qv * hreg[i][r];
        }
        #pragma unroll
        for (int r = 0; r < 16; r++) {
            float v = ph[r];
            v += __shfl_xor(v, 1); v += __shfl_xor(v, 2); v += __shfl_xor(v, 4);
            v += __shfl_xor(v, 8); v += __shfl_xor(v, 16);
            if (l31 == 0) s_ht2[hh][32 * g + (r & 3) + 8 * (r >> 2) + 4 * h5] = v;
        }
    }
    __syncthreads();
    if (tid < 128) s_feat[384 + tid] = (s_ht2[0][tid] + s_ht2[1][tid]) * frcp(s_scal[0]);
    __syncthreads();

    // ---------------- recurrence ----------------
    for (int t = 0; t < SS - 1; t++) {
        const float* qcur = s_q[t & 1];
        float*       qnxt = s_q[(t + 1) & 1];
        const int base = b * SS + t;
        const int e_t  = e_data[base];
        const int at_t = at_data[base];
        const int it_t = it_data[base];
        const float afl = (float)a_data[base];
        const int e_nx = e_data[base + 1];

        // --- MFMA at step top: logits from step t-1 fragments (ordered by B2..B7
        //     barriers vs the update-phase rewrite; acc=48 VGPR, lives to update) ---
        floatx16 acc[3];
        #pragma unroll
        for (int i = 0; i < 3; i++) acc[i] = (floatx16)(0.0f);
        #pragma unroll
        for (int i = 0; i < 3; i++) {
            if (i < ncb) {
                const int cb = cb0 + i;
                floatx16 a = (floatx16)(0.0f);
                #pragma unroll
                for (int kb = 0; kb < 8; kb++) {
                    short8v bf = *(const short8v*)((const char*)s_frag + (((kb * 5 + cb) << 10) + lane * 16));
                    a = __builtin_amdgcn_mfma_f32_32x32x16_bf16(afr[kb], bf, a, 0, 0, 0);
                }
                acc[i] = a;
            }
        }

        // --- staging ---
        if (w < 4) {
            const float* src; float* dst;
            if      (w == 0) { src = Ee  + (size_t)e_t  * DK; dst = s_eat; }
            else if (w == 1) { src = Eat + (size_t)at_t * DK; dst = s_eat + 128; }
            else if (w == 2) { src = Eit + (size_t)it_t * DK; dst = s_feat + 128; }
            else             { src = Ee  + (size_t)e_nx * DK; dst = s_enext; }
            ((float2*)dst)[lane] = ((const float2*)src)[lane];
        } else {
            int idx = tid - 256;
            if (idx < 160) qnxt[idx] = (idx < NQ1) ? qm[(size_t)e_nx * NQ1 + idx] : 0.0f;
        }
        __syncthreads();   // B1

        // --- phase A: all_learning partials (+ wave7 q_next sum) ---
        if (w == 7) {
            float v = qnxt[lane] + qnxt[64 + lane] + ((lane < 32) ? qnxt[128 + lane] : 0.0f);
            #pragma unroll
            for (int m = 32; m > 0; m >>= 1) v += __shfl_xor(v, m);
            if (lane == 0) s_scal[0] = v;
        }
        {
            const float4* rowp = (const float4*)(gmat ? (s_eat + 128) : s_eat);
            float4 fv = rowp[16 * hh + (lane & 15)];
            const float4* Wr = (const float4*)(ws + gmat * 16384);
            float z0 = 0.f, z1 = 0.f, z2 = 0.f, z3 = 0.f;
            #pragma unroll 8
            for (int s = 0; s < 16; s++) {
                float4 wv = Wr[(16 * hh + s) * 128 + gd];
                z0 += rlf(fv.x, s) * wv.x;  z1 += rlf(fv.y, s) * wv.y;
                z2 += rlf(fv.z, s) * wv.z;  z3 += rlf(fv.w, s) * wv.w;
            }
            s_red[(hh * 2 + gmat) * 128 + gd] = (z0 + z1) + (z2 + z3);
        }
        __syncthreads();   // B2
        if (tid < 128)
            s_feat[256 + tid] = b1[tid] + afl * s_s1[tid]
                              + s_red[tid] + s_red[128 + tid] + s_red[256 + tid] + s_red[384 + tid];
        __syncthreads();   // B3

        // --- phase B: feat(512) . W2 / W3, k split across halves ---
        {
            float4 fv = ((const float4*)s_feat)[64 * hh + lane];
            const float4* Wr = (const float4*)(ws + 32768 + gmat * 65536);
            float z0 = 0.f, z1 = 0.f, z2 = 0.f, z3 = 0.f;
            #pragma unroll 8
            for (int s = 0; s < 64; s++) {
                float4 wv = Wr[(64 * hh + s) * 128 + gd];
                z0 += rlf(fv.x, s) * wv.x;  z1 += rlf(fv.y, s) * wv.y;
                z2 += rlf(fv.z, s) * wv.z;  z3 += rlf(fv.w, s) * wv.w;
            }
            s_red[(hh * 2 + gmat) * 128 + gd] = (z0 + z1) + (z2 + z3);
        }
        __syncthreads();   // B4
        if (tid < 128) {
            float w2s = s_red[tid]       + s_red[256 + tid];
            float w3s = s_red[128 + tid] + s_red[384 + tid];
            s_LG[tid] = fsig(w3s + b3[tid]) * (ftanh(w2s + b2[tid]) + 1.0f) * 0.5f;
            s_feat[tid] = s_feat[256 + tid];   // lp <- lc
        }
        __syncthreads();   // B5

        // --- phase C: LG.W4l + it.W4i ---
        {
            const float4* rowp = (const float4*)(gmat ? (s_feat + 128) : s_LG);
            float4 fv = rowp[16 * hh + (lane & 15)];
            const float4* Wr = (const float4*)(ws + 163840 + gmat * 16384);
            float z0 = 0.f, z1 = 0.f, z2 = 0.f, z3 = 0.f;
            #pragma unroll 8
            for (int s = 0; s < 16; s++) {
                float4 wv = Wr[(16 * hh + s) * 128 + gd];
                z0 += rlf(fv.x, s) * wv.x;  z1 += rlf(fv.y, s) * wv.y;
                z2 += rlf(fv.z, s) * wv.z;  z3 += rlf(fv.w, s) * wv.w;
            }
            s_red[(hh * 2 + gmat) * 128 + gd] = (z0 + z1) + (z2 + z3);
        }
        __syncthreads();   // B6
        if (tid < 128)
            s_c[tid] = b4[tid] + s_red[tid] + s_red[128 + tid] + s_red[256 + tid] + s_red[384 + tid];
        __syncthreads();   // B7

        // --- update: h = q*LG + sigmoid(logit+c)*h ; new fragments + h_tilde ---
        {
            float lgv[16], cv[16];
            #pragma unroll
            for (int r = 0; r < 16; r++) {
                int d = 32 * g + (r & 3) + 8 * (r >> 2) + 4 * h5;
                lgv[r] = s_LG[d];  cv[r] = s_c[d];
            }
            float ph[16];
            #pragma unroll
            for (int r = 0; r < 16; r++) ph[r] = 0.0f;
            #pragma unroll
            for (int i = 0; i < 3; i++) {
                const bool act = (i < ncb);
                const int cb = act ? (cb0 + i) : 0;
                const int n = 32 * cb + l31;
                const float qcv = act ? qcur[n] : 0.0f;
                const float qnv = act ? qnxt[n] : 0.0f;
                const bool valid = act && ((cb < 4) || (l31 == 0));
                #pragma unroll
                for (int r = 0; r < 16; r++) {
                    float gg = fsig(acc[i][r] + cv[r]);
                    float hn = qcv * lgv[r] + gg * hreg[i][r];
                    hn = valid ? hn : 0.0f;
                    hreg[i][r] = hn;
                    ph[r] += qnv * hn;
                }
                if (act) {
                    #pragma unroll
                    for (int q = 0; q < 4; q++) {
                        int kb = 2 * g + (q >> 1);
                        int lanep = l31 + ((q & 1) << 5);
                        int off = (((kb * 5 + cb) << 10) + lanep * 16 + (h5 << 3)) >> 2;
                        unsigned lo = bfbits(hreg[i][4 * q])     | (bfbits(hreg[i][4 * q + 1]) << 16);
                        unsigned hi = bfbits(hreg[i][4 * q + 2]) | (bfbits(hreg[i][4 * q + 3]) << 16);
                        s_frag[off] = lo; s_frag[off + 1] = hi;
                    }
                }
            }
            #pragma unroll
            for (int r = 0; r < 16; r++) {
                float v = ph[r];
                v += __shfl_xor(v, 1); v += __shfl_xor(v, 2); v += __shfl_xor(v, 4);
                v += __shfl_xor(v, 8); v += __shfl_xor(v, 16);
                if (l31 == 0) s_ht2[hh][32 * g + (r & 3) + 8 * (r >> 2) + 4 * h5] = v;
            }
        }
        __syncthreads();   // B8
        if (tid < 128)
            s_feat[384 + tid] = (s_ht2[0][tid] + s_ht2[1][tid]) * frcp(s_scal[0]);
        __syncthreads();   // B9

        // --- phase E: [e_next, h_tilde] . W5 ---
        {
            const float4* rowp = (const float4*)(gmat ? (s_feat + 384) : s_enext);
            float4 fv = rowp[16 * hh + (lane & 15)];
            const float4* Wr = (const float4*)(ws + 196608 + gmat * 16384);
            float z0 = 0.f, z1 = 0.f, z2 = 0.f, z3 = 0.f;
            #pragma unroll 8
            for (int s = 0; s < 16; s++) {
                float4 wv = Wr[(16 * hh + s) * 128 + gd];
                z0 += rlf(fv.x, s) * wv.x;  z1 += rlf(fv.y, s) * wv.y;
                z2 += rlf(fv.z, s) * wv.z;  z3 += rlf(fv.w, s) * wv.w;
            }
            s_red[(hh * 2 + gmat) * 128 + gd] = (z0 + z1) + (z2 + z3);
        }
        __syncthreads();   // B10
        if (tid < 64) {
            float v = fsig(s_red[lane]      + s_red[128 + lane] + s_red[256 + lane] + s_red[384 + lane] + b5[lane])
                    + fsig(s_red[64 + lane] + s_red[192 + lane] + s_red[320 + lane] + s_red[448 + lane] + b5[64 + lane]);
            #pragma unroll
            for (int m = 32; m > 0; m >>= 1) v += __shfl_xor(v, m);
            if (lane == 0) out[base + 1] = v * (1.0f / 128.0f);
        }
        // no barrier needed: B1 of next iteration orders staging writes vs. readers
    }
}

extern "C" void kernel_launch(void* const* d_in, const int* in_sizes, int n_in,
                              void* d_out, int out_size, void* d_ws, size_t ws_size,
                              hipStream_t stream) {
    const int*   e_data  = (const int*)d_in[0];
    const int*   a_data  = (const int*)d_in[1];
    const int*   it_data = (const int*)d_in[2];
    const int*   at_data = (const int*)d_in[3];
    const float* qm  = (const float*)d_in[4];
    const float* h0  = (const float*)d_in[5];
    const float* Ee  = (const float*)d_in[6];
    const float* Eat = (const float*)d_in[7];
    const float* Eit = (const float*)d_in[8];
    const float* W1  = (const float*)d_in[9];
    const float* b1  = (const float*)d_in[10];
    const float* W2  = (const float*)d_in[11];
    const float* b2  = (const float*)d_in[12];
    const float* W3  = (const float*)d_in[13];
    const float* b3  = (const float*)d_in[14];
    const float* W4  = (const float*)d_in[15];
    const float* b4  = (const float*)d_in[16];
    const float* W5  = (const float*)d_in[17];
    const float* b5  = (const float*)d_in[18];
    float* out = (float*)d_out;
    float* ws  = (float*)d_ws;

    prep_kernel<<<dim3((WS_TOTAL + 255) / 256), dim3(256), 0, stream>>>(W1, W2, W3, W4, W5, ws);
    lpkt_kernel<<<dim3(BB), dim3(NTH), 0, stream>>>(
        e_data, a_data, it_data, at_data, qm, h0, Ee, Eat, Eit,
        W1, b1, W2, b2, W3, b3, W4, b4, W5, b5, out, ws);
}